// Round 3
// baseline (2724.918 us; speedup 1.0000x reference)
//
#include <hip/hip_runtime.h>

#define NODES 100000
#define NEDGE 1600000
#define NREL  3
#define DIN   128
#define DHID  128
#define DOUT  64

typedef unsigned short ushort_t;

__device__ __forceinline__ unsigned f2bf1(float f) {
    unsigned u = __float_as_uint(f);
    return (u + 0x7fffu + ((u >> 16) & 1u)) >> 16;   // RTNE f32->bf16
}
__device__ __forceinline__ float bf2f(ushort_t h) {
    return __uint_as_float((unsigned)h << 16);
}

// ---------------------------------------------------------------------------
// degree histogram, one edge per thread (fire-and-forget atomics pipeline)
__global__ __launch_bounds__(256) void deg_kernel(const int* __restrict__ edges,
                                                  unsigned* __restrict__ deg) {
    const int r = blockIdx.y;
    const int e = blockIdx.x * 256 + threadIdx.x;
    if (e >= NEDGE) return;
    const int* __restrict__ src = edges + (size_t)r * 2 * NEDGE;
    const int* __restrict__ dst = src + NEDGE;
    atomicAdd(&deg[r * NODES + src[e]], 1u);
    atomicAdd(&deg[(NREL + r) * NODES + dst[e]], 1u);
}

// exclusive scan of COMBINED in-degree (3 planes summed) -> rowptr + cursor
__global__ __launch_bounds__(1024) void scan_kernel(
    const unsigned* __restrict__ deg_in, int* __restrict__ rowptr,
    int* __restrict__ cursor) {
    __shared__ int wsum[16];
    __shared__ int carry_s, tile_total;
    const int tid = threadIdx.x, lane = tid & 63, wid = tid >> 6;
    if (tid == 0) carry_s = 0;
    __syncthreads();
    for (int base = 0; base < NODES; base += 1024) {
        const int i = base + tid;
        int v = 0;
        if (i < NODES) v = (int)(deg_in[i] + deg_in[NODES + i] + deg_in[2 * NODES + i]);
        int incl = v;
        for (int off = 1; off < 64; off <<= 1) {
            int t = __shfl_up(incl, off, 64);
            if (lane >= off) incl += t;
        }
        if (lane == 63) wsum[wid] = incl;
        __syncthreads();
        if (tid == 0) {
            int a = 0;
            for (int w = 0; w < 16; w++) { int t = wsum[w]; wsum[w] = a; a += t; }
            tile_total = a;
        }
        __syncthreads();
        if (i < NODES) {
            const int excl = carry_s + wsum[wid] + (incl - v);
            rowptr[i] = excl;
            cursor[i] = excl;
        }
        __syncthreads();
        if (tid == 0) carry_s += tile_total;
        __syncthreads();
    }
    if (tid == 0) rowptr[NODES] = carry_s;
}

// in-place uint degree -> float rsqrt(max(deg,1)), all 6 planes
__global__ void rsq_kernel(float* __restrict__ buf) {
    const int i = blockIdx.x * blockDim.x + threadIdx.x;
    if (i < 2 * NREL * NODES) {
        const unsigned d = ((const unsigned*)buf)[i];
        buf[i] = rsqrtf((float)(d ? d : 1u));
    }
}

// combined-CSR fill: entry = rel*NODES + src, one edge per thread
__global__ __launch_bounds__(256) void fill_kernel(const int* __restrict__ edges,
                                                   int* __restrict__ cursor,
                                                   int* __restrict__ csr) {
    const int r = blockIdx.y;
    const int e = blockIdx.x * 256 + threadIdx.x;
    if (e >= NEDGE) return;
    const int* __restrict__ src = edges + (size_t)r * 2 * NEDGE;
    const int* __restrict__ dst = src + NEDGE;
    const int pos = atomicAdd(&cursor[dst[e]], 1);
    csr[pos] = r * NODES + src[e];
}

// ---------------------------------------------------------------------------
// m[row,c] = rout[row] * sum_k A[row,k]*W[k,c], A bf16 (or f32->bf16), W f32,
// m bf16. 4x4 register tile/thread; W staged transposed in K=64 halves.
template <int ODIM, bool IN_BF16>
__global__ __launch_bounds__(256) void gemm_kernel(
    const void* __restrict__ A, const float* __restrict__ rout,
    const float* __restrict__ W, ushort_t* __restrict__ mout) {
    constexpr int COLG = ODIM / 4;      // 32 / 16
    constexpr int ROWS = 4096 / ODIM;   // 32 / 64
    constexpr int KT = 64;              // K tile for W staging
    constexpr int PADW = KT + 5;        // 69 floats: 5*cg mod 32 distinct -> conflict-free
    constexpr int PADK = DIN + 8;       // 136 ushorts
    extern __shared__ char lds_raw[];
    float* Wt = (float*)lds_raw;                              // [ODIM][PADW]
    ushort_t* Xs = (ushort_t*)(lds_raw + ODIM * PADW * 4);    // [ROWS][PADK]
    const int tid = threadIdx.x;
    const int row0 = blockIdx.x * ROWS;

    // stage A tile as bf16 (row-padded)
    for (int idx = tid * 8; idx < ROWS * DIN; idx += 2048) {
        const int rr = idx >> 7, kk = idx & (DIN - 1);
        const int row = row0 + rr;
        uint4 p;
        if (row < NODES) {
            if (IN_BF16) {
                p = *(const uint4*)((const ushort_t*)A + (size_t)row * DIN + kk);
            } else {
                const float* Af = (const float*)A + (size_t)row * DIN + kk;
                const float4 a = *(const float4*)Af;
                const float4 b = *(const float4*)(Af + 4);
                p.x = f2bf1(a.x) | (f2bf1(a.y) << 16);
                p.y = f2bf1(a.z) | (f2bf1(a.w) << 16);
                p.z = f2bf1(b.x) | (f2bf1(b.y) << 16);
                p.w = f2bf1(b.z) | (f2bf1(b.w) << 16);
            }
        } else { p.x = 0; p.y = 0; p.z = 0; p.w = 0; }
        *(uint4*)(Xs + rr * PADK + kk) = p;
    }

    const int cg = tid % COLG;
    const int rg = tid / COLG;
    const int r0 = rg * 4;
    float acc[4][4];
#pragma unroll
    for (int i = 0; i < 4; i++)
#pragma unroll
        for (int j = 0; j < 4; j++) acc[i][j] = 0.f;

    for (int kh = 0; kh < DIN; kh += KT) {
        __syncthreads();   // Xs ready (iter 0) / Wt reads done (iter 1)
        for (int idx = tid * 4; idx < KT * ODIM; idx += 1024) {
            const int k = idx / ODIM, c = idx % ODIM;
            const float4 w = *(const float4*)(W + (size_t)(kh + k) * ODIM + c);
            Wt[(c + 0) * PADW + k] = w.x;
            Wt[(c + 1) * PADW + k] = w.y;
            Wt[(c + 2) * PADW + k] = w.z;
            Wt[(c + 3) * PADW + k] = w.w;
        }
        __syncthreads();
#pragma unroll
        for (int kb = 0; kb < KT; kb += 8) {
            uint4 xr[4];
#pragma unroll
            for (int i = 0; i < 4; i++)
                xr[i] = *(const uint4*)(Xs + (r0 + i) * PADK + kh + kb);
            float4 wa[4], wb[4];
#pragma unroll
            for (int j = 0; j < 4; j++) {
                const float* wp = Wt + (cg + j * COLG) * PADW + kb;
                wa[j] = *(const float4*)wp;
                wb[j] = *(const float4*)(wp + 4);
            }
#pragma unroll
            for (int i = 0; i < 4; i++) {
                const float x0 = __uint_as_float(xr[i].x << 16);
                const float x1 = __uint_as_float(xr[i].x & 0xffff0000u);
                const float x2 = __uint_as_float(xr[i].y << 16);
                const float x3 = __uint_as_float(xr[i].y & 0xffff0000u);
                const float x4 = __uint_as_float(xr[i].z << 16);
                const float x5 = __uint_as_float(xr[i].z & 0xffff0000u);
                const float x6 = __uint_as_float(xr[i].w << 16);
                const float x7 = __uint_as_float(xr[i].w & 0xffff0000u);
#pragma unroll
                for (int j = 0; j < 4; j++) {
                    acc[i][j] += x0 * wa[j].x + x1 * wa[j].y + x2 * wa[j].z +
                                 x3 * wa[j].w + x4 * wb[j].x + x5 * wb[j].y +
                                 x6 * wb[j].z + x7 * wb[j].w;
                }
            }
        }
    }
#pragma unroll
    for (int i = 0; i < 4; i++) {
        const int row = row0 + r0 + i;
        if (row >= NODES) break;
        const float sc = rout[row];
        ushort_t* op = mout + (size_t)row * ODIM + cg;
#pragma unroll
        for (int j = 0; j < 4; j++) op[j * COLG] = (ushort_t)f2bf1(acc[i][j] * sc);
    }
}

// ---------------------------------------------------------------------------
// combined pull-agg over all relations + fused bias/relu epilogue.
// entry p = rel*NODES+src; per-edge scale = rin[rel][v] selected from 3 regs.
template <int ODIM, bool L1>
__global__ __launch_bounds__(256) void agg_kernel(
    const ushort_t* __restrict__ m, const int* __restrict__ rowptr,
    const int* __restrict__ csr, const float* __restrict__ rin,
    const float* __restrict__ bias, float* __restrict__ outf,
    ushort_t* __restrict__ outh) {
    constexpr int NPB = 256 / ODIM;
    const int v = blockIdx.x * NPB + threadIdx.x / ODIM;
    const int col = threadIdx.x & (ODIM - 1);
    const int b = rowptr[v], e = rowptr[v + 1];
    const float s0 = rin[v], s1 = rin[NODES + v], s2 = rin[2 * NODES + v];
    float sum = 0.f;
    int i = b;
    for (; i + 3 < e; i += 4) {
        const int p0 = csr[i], p1 = csr[i + 1], p2 = csr[i + 2], p3 = csr[i + 3];
        const float f0 = bf2f(m[(size_t)p0 * ODIM + col]);
        const float f1 = bf2f(m[(size_t)p1 * ODIM + col]);
        const float f2 = bf2f(m[(size_t)p2 * ODIM + col]);
        const float f3 = bf2f(m[(size_t)p3 * ODIM + col]);
        const float c0 = p0 < NODES ? s0 : (p0 < 2 * NODES ? s1 : s2);
        const float c1 = p1 < NODES ? s0 : (p1 < 2 * NODES ? s1 : s2);
        const float c2 = p2 < NODES ? s0 : (p2 < 2 * NODES ? s1 : s2);
        const float c3 = p3 < NODES ? s0 : (p3 < 2 * NODES ? s1 : s2);
        sum += f0 * c0; sum += f1 * c1; sum += f2 * c2; sum += f3 * c3;
    }
    for (; i < e; i++) {
        const int p = csr[i];
        const float sc = p < NODES ? s0 : (p < 2 * NODES ? s1 : s2);
        sum += bf2f(m[(size_t)p * ODIM + col]) * sc;
    }
    const float bsum = bias[col] + bias[ODIM + col] + bias[2 * ODIM + col];
    if (L1) {
        outh[(size_t)v * ODIM + col] = (ushort_t)f2bf1(fmaxf(sum + bsum, 0.f));
    } else {
        outf[(size_t)v * ODIM + col] = sum + bsum;
    }
}

// ---------------------------------------------------------------------------
extern "C" void kernel_launch(void* const* d_in, const int* in_sizes, int n_in,
                              void* d_out, int out_size, void* d_ws, size_t ws_size,
                              hipStream_t stream) {
    const float* x  = (const float*)d_in[0];
    const int* edges = (const int*)d_in[1];
    const float* W1 = (const float*)d_in[2];
    const float* b1 = (const float*)d_in[3];
    const float* W2 = (const float*)d_in[4];
    const float* b2 = (const float*)d_in[5];
    float* out = (float*)d_out;

    char* ws = (char*)d_ws;
    size_t off = 0;
    auto alloc = [&](size_t bytes) {
        void* p = ws + off;
        off = (off + bytes + 255) & ~(size_t)255;
        return p;
    };
    float*    rsq    = (float*)alloc((size_t)2 * NREL * NODES * 4);   // 2.4 MB
    int*      rowptr = (int*)alloc((size_t)(NODES + 1) * 4);
    int*      cursor = (int*)alloc((size_t)NODES * 4);
    int*      csr    = (int*)alloc((size_t)NREL * NEDGE * 4);         // 19.2 MB
    ushort_t* m_all  = (ushort_t*)alloc((size_t)NREL * NODES * DHID * 2); // 76.8 MB
    ushort_t* h      = (ushort_t*)alloc((size_t)NODES * DHID * 2);    // 25.6 MB
    // total ~125 MB (within proven ws budget)

    const dim3 egrid(NEDGE / 256, NREL);
    hipMemsetAsync(rsq, 0, (size_t)2 * NREL * NODES * 4, stream);
    deg_kernel<<<egrid, 256, 0, stream>>>(edges, (unsigned*)rsq);
    scan_kernel<<<1, 1024, 0, stream>>>((const unsigned*)rsq + (size_t)NREL * NODES,
                                        rowptr, cursor);
    rsq_kernel<<<(2 * NREL * NODES + 255) / 256, 256, 0, stream>>>(rsq);
    fill_kernel<<<egrid, 256, 0, stream>>>(edges, cursor, csr);

    const float* rin = rsq + (size_t)NREL * NODES;
    const int lds1 = DHID * (64 + 5) * 4 + (4096 / DHID) * (DIN + 8) * 2;  // 44 KB
    const int lds2 = DOUT * (64 + 5) * 4 + (4096 / DOUT) * (DIN + 8) * 2;  // 35 KB

    // --- layer 1: 3 GEMMs (x f32 -> bf16) + one combined agg (fused relu+bias)
    for (int r = 0; r < NREL; r++)
        gemm_kernel<DHID, false><<<(NODES + 31) / 32, 256, lds1, stream>>>(
            x, rsq + (size_t)r * NODES, W1 + (size_t)r * DIN * DHID,
            m_all + (size_t)r * NODES * DHID);
    agg_kernel<DHID, true><<<NODES / 2, 256, 0, stream>>>(
        m_all, rowptr, csr, rin, b1, nullptr, h);

    // --- layer 2: 3 GEMMs (h bf16) + combined agg writing d_out (fused bias)
    for (int r = 0; r < NREL; r++)
        gemm_kernel<DOUT, true><<<(NODES + 63) / 64, 256, lds2, stream>>>(
            h, rsq + (size_t)r * NODES, W2 + (size_t)r * DHID * DOUT,
            m_all + (size_t)r * NODES * DOUT);
    agg_kernel<DOUT, false><<<NODES / 4, 256, 0, stream>>>(
        m_all, rowptr, csr, rin, b2, out, nullptr);
}

// Round 4
// 2115.287 us; speedup vs baseline: 1.2882x; 1.2882x over previous
//
#include <hip/hip_runtime.h>

#define NODES 100000
#define NEDGE 1600000
#define NREL  3
#define DIN   128
#define DHID  128
#define DOUT  64

#define NBUCK 782      // ceil(NODES/128), bucket = 128 dst nodes
#define CHUNK 24576    // edges per block in count/partition
#define NBLK  66       // ceil(NEDGE/CHUNK)
#define SEGCAP 8192    // per-bucket edge cap (mean 6144, sigma 78 -> +26 sigma)

typedef unsigned short ushort_t;

__device__ __forceinline__ unsigned f2bf1(float f) {
    unsigned u = __float_as_uint(f);
    return (u + 0x7fffu + ((u >> 16) & 1u)) >> 16;   // RTNE f32->bf16
}
__device__ __forceinline__ float bf2f(ushort_t h) {
    return __uint_as_float((unsigned)h << 16);
}

// ---------------------------------------------------------------------------
// out-degree atomics (src side) + dst-bucket histogram via LDS
__global__ __launch_bounds__(256) void count_kernel(
    const int* __restrict__ edges, unsigned* __restrict__ degOut,
    unsigned* __restrict__ bucketTotal) {
    __shared__ unsigned hist[NBUCK];
    const int r = blockIdx.y;
    const int e0 = blockIdx.x * CHUNK;
    const int e1 = min(e0 + CHUNK, NEDGE);
    const int* __restrict__ src = edges + (size_t)r * 2 * NEDGE;
    const int* __restrict__ dst = src + NEDGE;
    for (int i = threadIdx.x; i < NBUCK; i += 256) hist[i] = 0;
    __syncthreads();
    for (int e = e0 + threadIdx.x; e < e1; e += 256) {
        atomicAdd(&degOut[r * NODES + src[e]], 1u);
        atomicAdd(&hist[dst[e] >> 7], 1u);
    }
    __syncthreads();
    for (int i = threadIdx.x; i < NBUCK; i += 256) {
        const unsigned c = hist[i];
        if (c) atomicAdd(&bucketTotal[i], c);
    }
}

// scan 782 bucket totals -> bucketBase[783]; init blockCursor
__global__ __launch_bounds__(1024) void bscan_kernel(
    const unsigned* __restrict__ bucketTotal, int* __restrict__ bucketBase,
    int* __restrict__ blockCursor) {
    __shared__ int wsum[16];
    const int tid = threadIdx.x, lane = tid & 63, wid = tid >> 6;
    const int v = (tid < NBUCK) ? (int)bucketTotal[tid] : 0;
    int incl = v;
    for (int off = 1; off < 64; off <<= 1) {
        const int t = __shfl_up(incl, off, 64);
        if (lane >= off) incl += t;
    }
    if (lane == 63) wsum[wid] = incl;
    __syncthreads();
    if (tid == 0) {
        int a = 0;
        for (int w = 0; w < 16; w++) { const int t = wsum[w]; wsum[w] = a; a += t; }
    }
    __syncthreads();
    const int excl = wsum[wid] + incl - v;
    if (tid <= NBUCK) bucketBase[tid] = excl;
    if (tid < NBUCK) blockCursor[tid] = excl;
}

// in-place uint out-degree -> float rsqrt(max(deg,1)), 3 planes
__global__ void rsq_kernel(float* __restrict__ buf) {
    const int i = blockIdx.x * blockDim.x + threadIdx.x;
    if (i < NREL * NODES) {
        const unsigned d = ((const unsigned*)buf)[i];
        buf[i] = rsqrtf((float)(d ? d : 1u));
    }
}

// bucket-partition edges: block reserves per-bucket runs, writes packed u32
__global__ __launch_bounds__(256) void partition_kernel(
    const int* __restrict__ edges, int* __restrict__ blockCursor,
    unsigned* __restrict__ inter) {
    __shared__ unsigned hist[NBUCK];
    __shared__ unsigned resv[NBUCK];
    const int r = blockIdx.y;
    const int e0 = blockIdx.x * CHUNK;
    const int e1 = min(e0 + CHUNK, NEDGE);
    const int* __restrict__ src = edges + (size_t)r * 2 * NEDGE;
    const int* __restrict__ dst = src + NEDGE;
    for (int i = threadIdx.x; i < NBUCK; i += 256) hist[i] = 0;
    __syncthreads();
    for (int e = e0 + threadIdx.x; e < e1; e += 256)
        atomicAdd(&hist[dst[e] >> 7], 1u);
    __syncthreads();
    for (int i = threadIdx.x; i < NBUCK; i += 256) {
        const unsigned c = hist[i];
        resv[i] = c ? (unsigned)atomicAdd(&blockCursor[i], (int)c) : 0u;
        hist[i] = 0;   // becomes rank cursor (each i owned by one thread)
    }
    __syncthreads();
    for (int e = e0 + threadIdx.x; e < e1; e += 256) {
        const int d = dst[e];
        const int b = d >> 7;
        const unsigned rank = atomicAdd(&hist[b], 1u);
        inter[resv[b] + rank] =
            ((unsigned)(d & 127) << 19) | (unsigned)(r * NODES + src[e]);
    }
}

// per-bucket CSR build fully in LDS; coalesced global writes; rin written here
__global__ __launch_bounds__(256) void build_kernel(
    const unsigned* __restrict__ inter, const int* __restrict__ bucketBase,
    int* __restrict__ csr, int* __restrict__ rowptr, float* __restrict__ rin) {
    __shared__ int degR[NREL][128];
    __shared__ int rp[129];
    __shared__ int cur[128];
    __shared__ int csr_lds[SEGCAP];
    const int b = blockIdx.x;
    const int tid = threadIdx.x;
    const int n0 = b << 7;
    const int nn = min(128, NODES - n0);
    const int s0 = bucketBase[b], s1 = bucketBase[b + 1];
    for (int i = tid; i < NREL * 128; i += 256) ((int*)degR)[i] = 0;
    __syncthreads();
    for (int s = s0 + tid; s < s1; s += 256) {
        const unsigned w = inter[s];
        const int dl = w >> 19;
        const int p = (int)(w & 0x7FFFFu);
        const int rel = p < NODES ? 0 : (p < 2 * NODES ? 1 : 2);
        atomicAdd(&degR[rel][dl], 1);
    }
    __syncthreads();
    if (tid == 0) {
        int a = 0;
        for (int i = 0; i < 128; i++) {
            rp[i] = a;
            cur[i] = a;
            a += degR[0][i] + degR[1][i] + degR[2][i];
        }
        rp[128] = a;
    }
    __syncthreads();
    if (tid < nn) {
        const int node = n0 + tid;
        rowptr[node] = s0 + rp[tid];
#pragma unroll
        for (int r = 0; r < NREL; r++) {
            const int d = degR[r][tid];
            rin[r * NODES + node] = rsqrtf((float)(d ? d : 1));
        }
    }
    if (b == NBUCK - 1 && tid == 0) rowptr[NODES] = s1;
    for (int s = s0 + tid; s < s1; s += 256) {
        const unsigned w = inter[s];
        const int dl = w >> 19;
        const int slot = atomicAdd(&cur[dl], 1);
        csr_lds[slot] = (int)(w & 0x7FFFFu);
    }
    __syncthreads();
    const int len = s1 - s0;
    for (int i = tid; i < len; i += 256) csr[s0 + i] = csr_lds[i];
}

// ---------------------------------------------------------------------------
// m[row,c] = rout[row] * sum_k A[row,k]*W[k,c], A bf16 (or f32->bf16), W f32,
// m bf16. 4x4 register tile/thread; W staged transposed in K=64 halves.
template <int ODIM, bool IN_BF16>
__global__ __launch_bounds__(256) void gemm_kernel(
    const void* __restrict__ A, const float* __restrict__ rout,
    const float* __restrict__ W, ushort_t* __restrict__ mout) {
    constexpr int COLG = ODIM / 4;
    constexpr int ROWS = 4096 / ODIM;
    constexpr int KT = 64;
    constexpr int PADW = KT + 5;
    constexpr int PADK = DIN + 8;
    extern __shared__ char lds_raw[];
    float* Wt = (float*)lds_raw;                              // [ODIM][PADW]
    ushort_t* Xs = (ushort_t*)(lds_raw + ODIM * PADW * 4);    // [ROWS][PADK]
    const int tid = threadIdx.x;
    const int row0 = blockIdx.x * ROWS;

    for (int idx = tid * 8; idx < ROWS * DIN; idx += 2048) {
        const int rr = idx >> 7, kk = idx & (DIN - 1);
        const int row = row0 + rr;
        uint4 p;
        if (row < NODES) {
            if (IN_BF16) {
                p = *(const uint4*)((const ushort_t*)A + (size_t)row * DIN + kk);
            } else {
                const float* Af = (const float*)A + (size_t)row * DIN + kk;
                const float4 a = *(const float4*)Af;
                const float4 b = *(const float4*)(Af + 4);
                p.x = f2bf1(a.x) | (f2bf1(a.y) << 16);
                p.y = f2bf1(a.z) | (f2bf1(a.w) << 16);
                p.z = f2bf1(b.x) | (f2bf1(b.y) << 16);
                p.w = f2bf1(b.z) | (f2bf1(b.w) << 16);
            }
        } else { p.x = 0; p.y = 0; p.z = 0; p.w = 0; }
        *(uint4*)(Xs + rr * PADK + kk) = p;
    }

    const int cg = tid % COLG;
    const int rg = tid / COLG;
    const int r0 = rg * 4;
    float acc[4][4];
#pragma unroll
    for (int i = 0; i < 4; i++)
#pragma unroll
        for (int j = 0; j < 4; j++) acc[i][j] = 0.f;

    for (int kh = 0; kh < DIN; kh += KT) {
        __syncthreads();
        for (int idx = tid * 4; idx < KT * ODIM; idx += 1024) {
            const int k = idx / ODIM, c = idx % ODIM;
            const float4 w = *(const float4*)(W + (size_t)(kh + k) * ODIM + c);
            Wt[(c + 0) * PADW + k] = w.x;
            Wt[(c + 1) * PADW + k] = w.y;
            Wt[(c + 2) * PADW + k] = w.z;
            Wt[(c + 3) * PADW + k] = w.w;
        }
        __syncthreads();
#pragma unroll
        for (int kb = 0; kb < KT; kb += 8) {
            uint4 xr[4];
#pragma unroll
            for (int i = 0; i < 4; i++)
                xr[i] = *(const uint4*)(Xs + (r0 + i) * PADK + kh + kb);
            float4 wa[4], wb[4];
#pragma unroll
            for (int j = 0; j < 4; j++) {
                const float* wp = Wt + (cg + j * COLG) * PADW + kb;
                wa[j] = *(const float4*)wp;
                wb[j] = *(const float4*)(wp + 4);
            }
#pragma unroll
            for (int i = 0; i < 4; i++) {
                const float x0 = __uint_as_float(xr[i].x << 16);
                const float x1 = __uint_as_float(xr[i].x & 0xffff0000u);
                const float x2 = __uint_as_float(xr[i].y << 16);
                const float x3 = __uint_as_float(xr[i].y & 0xffff0000u);
                const float x4 = __uint_as_float(xr[i].z << 16);
                const float x5 = __uint_as_float(xr[i].z & 0xffff0000u);
                const float x6 = __uint_as_float(xr[i].w << 16);
                const float x7 = __uint_as_float(xr[i].w & 0xffff0000u);
#pragma unroll
                for (int j = 0; j < 4; j++) {
                    acc[i][j] += x0 * wa[j].x + x1 * wa[j].y + x2 * wa[j].z +
                                 x3 * wa[j].w + x4 * wb[j].x + x5 * wb[j].y +
                                 x6 * wb[j].z + x7 * wb[j].w;
                }
            }
        }
    }
#pragma unroll
    for (int i = 0; i < 4; i++) {
        const int row = row0 + r0 + i;
        if (row >= NODES) break;
        const float sc = rout[row];
        ushort_t* op = mout + (size_t)row * ODIM + cg;
#pragma unroll
        for (int j = 0; j < 4; j++) op[j * COLG] = (ushort_t)f2bf1(acc[i][j] * sc);
    }
}

// ---------------------------------------------------------------------------
// combined pull-agg over all relations + fused bias/relu epilogue.
template <int ODIM, bool L1>
__global__ __launch_bounds__(256) void agg_kernel(
    const ushort_t* __restrict__ m, const int* __restrict__ rowptr,
    const int* __restrict__ csr, const float* __restrict__ rin,
    const float* __restrict__ bias, float* __restrict__ outf,
    ushort_t* __restrict__ outh) {
    constexpr int NPB = 256 / ODIM;
    const int v = blockIdx.x * NPB + threadIdx.x / ODIM;
    const int col = threadIdx.x & (ODIM - 1);
    const int b = rowptr[v], e = rowptr[v + 1];
    const float s0 = rin[v], s1 = rin[NODES + v], s2 = rin[2 * NODES + v];
    float sum = 0.f;
    int i = b;
    for (; i + 3 < e; i += 4) {
        const int p0 = csr[i], p1 = csr[i + 1], p2 = csr[i + 2], p3 = csr[i + 3];
        const float f0 = bf2f(m[(size_t)p0 * ODIM + col]);
        const float f1 = bf2f(m[(size_t)p1 * ODIM + col]);
        const float f2 = bf2f(m[(size_t)p2 * ODIM + col]);
        const float f3 = bf2f(m[(size_t)p3 * ODIM + col]);
        const float c0 = p0 < NODES ? s0 : (p0 < 2 * NODES ? s1 : s2);
        const float c1 = p1 < NODES ? s0 : (p1 < 2 * NODES ? s1 : s2);
        const float c2 = p2 < NODES ? s0 : (p2 < 2 * NODES ? s1 : s2);
        const float c3 = p3 < NODES ? s0 : (p3 < 2 * NODES ? s1 : s2);
        sum += f0 * c0; sum += f1 * c1; sum += f2 * c2; sum += f3 * c3;
    }
    for (; i < e; i++) {
        const int p = csr[i];
        const float sc = p < NODES ? s0 : (p < 2 * NODES ? s1 : s2);
        sum += bf2f(m[(size_t)p * ODIM + col]) * sc;
    }
    const float bsum = bias[col] + bias[ODIM + col] + bias[2 * ODIM + col];
    if (L1) {
        outh[(size_t)v * ODIM + col] = (ushort_t)f2bf1(fmaxf(sum + bsum, 0.f));
    } else {
        outf[(size_t)v * ODIM + col] = sum + bsum;
    }
}

// ---------------------------------------------------------------------------
extern "C" void kernel_launch(void* const* d_in, const int* in_sizes, int n_in,
                              void* d_out, int out_size, void* d_ws, size_t ws_size,
                              hipStream_t stream) {
    const float* x  = (const float*)d_in[0];
    const int* edges = (const int*)d_in[1];
    const float* W1 = (const float*)d_in[2];
    const float* b1 = (const float*)d_in[3];
    const float* W2 = (const float*)d_in[4];
    const float* b2 = (const float*)d_in[5];
    float* out = (float*)d_out;

    char* ws = (char*)d_ws;
    size_t off = 0;
    auto alloc = [&](size_t bytes) {
        void* p = ws + off;
        off = (off + bytes + 255) & ~(size_t)255;
        return p;
    };
    // rout (3N) and bucketTotal adjacent -> single memset
    float*    rout   = (float*)alloc(((size_t)NREL * NODES + NBUCK) * 4);
    unsigned* btot   = (unsigned*)rout + (size_t)NREL * NODES;
    float*    rin    = (float*)alloc((size_t)NREL * NODES * 4);
    int*      bbase  = (int*)alloc((size_t)(NBUCK + 1) * 4);
    int*      bcur   = (int*)alloc((size_t)NBUCK * 4);
    int*      rowptr = (int*)alloc((size_t)(NODES + 1) * 4);
    int*      csr    = (int*)alloc((size_t)NREL * NEDGE * 4);             // 19.2 MB
    ushort_t* m_all  = (ushort_t*)alloc((size_t)NREL * NODES * DHID * 2); // 76.8 MB
    ushort_t* h      = (ushort_t*)alloc((size_t)NODES * DHID * 2);        // 25.6 MB
    unsigned* inter  = (unsigned*)m_all;  // overlay: dead before first gemm write

    // --- CSR build (shared by both layers) ---
    hipMemsetAsync(rout, 0, ((size_t)NREL * NODES + NBUCK) * 4, stream);
    count_kernel<<<dim3(NBLK, NREL), 256, 0, stream>>>(edges, (unsigned*)rout, btot);
    bscan_kernel<<<1, 1024, 0, stream>>>(btot, bbase, bcur);
    rsq_kernel<<<(NREL * NODES + 255) / 256, 256, 0, stream>>>(rout);
    partition_kernel<<<dim3(NBLK, NREL), 256, 0, stream>>>(edges, bcur, inter);
    build_kernel<<<NBUCK, 256, 0, stream>>>(inter, bbase, csr, rowptr, rin);

    const int lds1 = DHID * (64 + 5) * 4 + (4096 / DHID) * (DIN + 8) * 2;  // 44 KB
    const int lds2 = DOUT * (64 + 5) * 4 + (4096 / DOUT) * (DIN + 8) * 2;  // 35 KB

    // --- layer 1 ---
    for (int r = 0; r < NREL; r++)
        gemm_kernel<DHID, false><<<(NODES + 31) / 32, 256, lds1, stream>>>(
            x, rout + (size_t)r * NODES, W1 + (size_t)r * DIN * DHID,
            m_all + (size_t)r * NODES * DHID);
    agg_kernel<DHID, true><<<NODES / 2, 256, 0, stream>>>(
        m_all, rowptr, csr, rin, b1, nullptr, h);

    // --- layer 2 ---
    for (int r = 0; r < NREL; r++)
        gemm_kernel<DOUT, true><<<(NODES + 63) / 64, 256, lds2, stream>>>(
            h, rout + (size_t)r * NODES, W2 + (size_t)r * DHID * DOUT,
            m_all + (size_t)r * NODES * DOUT);
    agg_kernel<DOUT, false><<<NODES / 4, 256, 0, stream>>>(
        m_all, rowptr, csr, rin, b2, out, nullptr);
}

// Round 5
// 820.501 us; speedup vs baseline: 3.3210x; 2.5780x over previous
//
#include <hip/hip_runtime.h>

#define NODES 100000
#define NEDGE 1600000
#define NREL  3
#define DIN   128
#define DHID  128
#define DOUT  64

#define NBUCK 782      // ceil(NODES/128), bucket = 128 dst nodes
#define CHUNK 24576    // edges per block in count/partition
#define NBLK  66       // ceil(NEDGE/CHUNK)
#define SEGCAP 8192    // per-bucket edge cap (mean 6144 -> +26 sigma)

typedef unsigned short ushort_t;
typedef __attribute__((ext_vector_type(8))) short bf16x8;
typedef __attribute__((ext_vector_type(4))) float f32x4;

__device__ __forceinline__ unsigned f2bf1(float f) {
    unsigned u = __float_as_uint(f);
    return (u + 0x7fffu + ((u >> 16) & 1u)) >> 16;   // RTNE f32->bf16
}
__device__ __forceinline__ float bf2f(ushort_t h) {
    return __uint_as_float((unsigned)h << 16);
}

// ---------------------------------------------------------------------------
// out-degree atomics (src side) + dst-bucket histogram via LDS
__global__ __launch_bounds__(256) void count_kernel(
    const int* __restrict__ edges, unsigned* __restrict__ degOut,
    unsigned* __restrict__ bucketTotal) {
    __shared__ unsigned hist[NBUCK];
    const int r = blockIdx.y;
    const int e0 = blockIdx.x * CHUNK;
    const int e1 = min(e0 + CHUNK, NEDGE);
    const int* __restrict__ src = edges + (size_t)r * 2 * NEDGE;
    const int* __restrict__ dst = src + NEDGE;
    for (int i = threadIdx.x; i < NBUCK; i += 256) hist[i] = 0;
    __syncthreads();
    for (int e = e0 + threadIdx.x; e < e1; e += 256) {
        atomicAdd(&degOut[r * NODES + src[e]], 1u);
        atomicAdd(&hist[dst[e] >> 7], 1u);
    }
    __syncthreads();
    for (int i = threadIdx.x; i < NBUCK; i += 256) {
        const unsigned c = hist[i];
        if (c) atomicAdd(&bucketTotal[i], c);
    }
}

// scan 782 bucket totals -> bucketBase[783]; init blockCursor
__global__ __launch_bounds__(1024) void bscan_kernel(
    const unsigned* __restrict__ bucketTotal, int* __restrict__ bucketBase,
    int* __restrict__ blockCursor) {
    __shared__ int wsum[16];
    const int tid = threadIdx.x, lane = tid & 63, wid = tid >> 6;
    const int v = (tid < NBUCK) ? (int)bucketTotal[tid] : 0;
    int incl = v;
    for (int off = 1; off < 64; off <<= 1) {
        const int t = __shfl_up(incl, off, 64);
        if (lane >= off) incl += t;
    }
    if (lane == 63) wsum[wid] = incl;
    __syncthreads();
    if (tid == 0) {
        int a = 0;
        for (int w = 0; w < 16; w++) { const int t = wsum[w]; wsum[w] = a; a += t; }
    }
    __syncthreads();
    const int excl = wsum[wid] + incl - v;
    if (tid <= NBUCK) bucketBase[tid] = excl;
    if (tid < NBUCK) blockCursor[tid] = excl;
}

// in-place uint out-degree -> float rsqrt(max(deg,1)), 3 planes
__global__ void rsq_kernel(float* __restrict__ buf) {
    const int i = blockIdx.x * blockDim.x + threadIdx.x;
    if (i < NREL * NODES) {
        const unsigned d = ((const unsigned*)buf)[i];
        buf[i] = rsqrtf((float)(d ? d : 1u));
    }
}

// bucket-partition edges: block reserves per-bucket runs, writes packed u32
__global__ __launch_bounds__(256) void partition_kernel(
    const int* __restrict__ edges, int* __restrict__ blockCursor,
    unsigned* __restrict__ inter) {
    __shared__ unsigned hist[NBUCK];
    __shared__ unsigned resv[NBUCK];
    const int r = blockIdx.y;
    const int e0 = blockIdx.x * CHUNK;
    const int e1 = min(e0 + CHUNK, NEDGE);
    const int* __restrict__ src = edges + (size_t)r * 2 * NEDGE;
    const int* __restrict__ dst = src + NEDGE;
    for (int i = threadIdx.x; i < NBUCK; i += 256) hist[i] = 0;
    __syncthreads();
    for (int e = e0 + threadIdx.x; e < e1; e += 256)
        atomicAdd(&hist[dst[e] >> 7], 1u);
    __syncthreads();
    for (int i = threadIdx.x; i < NBUCK; i += 256) {
        const unsigned c = hist[i];
        resv[i] = c ? (unsigned)atomicAdd(&blockCursor[i], (int)c) : 0u;
        hist[i] = 0;   // becomes rank cursor
    }
    __syncthreads();
    for (int e = e0 + threadIdx.x; e < e1; e += 256) {
        const int d = dst[e];
        const int b = d >> 7;
        const unsigned rank = atomicAdd(&hist[b], 1u);
        inter[resv[b] + rank] =
            ((unsigned)(d & 127) << 19) | (unsigned)(r * NODES + src[e]);
    }
}

// per-bucket CSR build fully in LDS; coalesced global writes; rin written here
__global__ __launch_bounds__(256) void build_kernel(
    const unsigned* __restrict__ inter, const int* __restrict__ bucketBase,
    int* __restrict__ csr, int* __restrict__ rowptr, float* __restrict__ rin) {
    __shared__ int degR[NREL][128];
    __shared__ int rp[129];
    __shared__ int cur[128];
    __shared__ int csr_lds[SEGCAP];
    const int b = blockIdx.x;
    const int tid = threadIdx.x;
    const int n0 = b << 7;
    const int nn = min(128, NODES - n0);
    const int s0 = bucketBase[b], s1 = bucketBase[b + 1];
    for (int i = tid; i < NREL * 128; i += 256) ((int*)degR)[i] = 0;
    __syncthreads();
    for (int s = s0 + tid; s < s1; s += 256) {
        const unsigned w = inter[s];
        const int dl = w >> 19;
        const int p = (int)(w & 0x7FFFFu);
        const int rel = p < NODES ? 0 : (p < 2 * NODES ? 1 : 2);
        atomicAdd(&degR[rel][dl], 1);
    }
    __syncthreads();
    if (tid == 0) {
        int a = 0;
        for (int i = 0; i < 128; i++) {
            rp[i] = a;
            cur[i] = a;
            a += degR[0][i] + degR[1][i] + degR[2][i];
        }
        rp[128] = a;
    }
    __syncthreads();
    if (tid < nn) {
        const int node = n0 + tid;
        rowptr[node] = s0 + rp[tid];
#pragma unroll
        for (int r = 0; r < NREL; r++) {
            const int d = degR[r][tid];
            rin[r * NODES + node] = rsqrtf((float)(d ? d : 1));
        }
    }
    if (b == NBUCK - 1 && tid == 0) rowptr[NODES] = s1;
    for (int s = s0 + tid; s < s1; s += 256) {
        const unsigned w = inter[s];
        const int dl = w >> 19;
        const int slot = atomicAdd(&cur[dl], 1);
        csr_lds[slot] = (int)(w & 0x7FFFFu);
    }
    __syncthreads();
    const int len = s1 - s0;
    for (int i = tid; i < len; i += 256) csr[s0 + i] = csr_lds[i];
}

// ---------------------------------------------------------------------------
// f32 -> bf16 pre-pass (8 elems/thread)
__global__ __launch_bounds__(256) void tobf_kernel(const float* __restrict__ x,
                                                   ushort_t* __restrict__ xb) {
    const size_t i = ((size_t)blockIdx.x * 256 + threadIdx.x) * 8;
    const float4 a = *(const float4*)(x + i);
    const float4 b = *(const float4*)(x + i + 4);
    uint4 p;
    p.x = f2bf1(a.x) | (f2bf1(a.y) << 16);
    p.y = f2bf1(a.z) | (f2bf1(a.w) << 16);
    p.z = f2bf1(b.x) | (f2bf1(b.y) << 16);
    p.w = f2bf1(b.z) | (f2bf1(b.w) << 16);
    *(uint4*)(xb + i) = p;
}

// ---------------------------------------------------------------------------
// MFMA GEMM: m_all[rel][row][c] = rout[rel][row] * sum_k A[row][k] * W[rel][k][c]
// A bf16 [NODES][DIN]; W f32 -> bf16 staged transposed in LDS; 16x16x32 MFMA.
// block = 256 thr (4 waves) x 64 rows; grid.y = relation.
template <int ODIM>
__global__ __launch_bounds__(256) void mfma_gemm(
    const ushort_t* __restrict__ A, const float* __restrict__ rout_all,
    const float* __restrict__ W_all, ushort_t* __restrict__ m_all) {
    constexpr int PAD = DIN + 8;    // 136: frag reads land on the 8/bank-group floor
    constexpr int NT = ODIM / 16;   // 8 or 4 column tiles per wave
    __shared__ ushort_t Al[64 * PAD];
    __shared__ ushort_t Wt[ODIM * PAD];
    const int tid = threadIdx.x;
    const int rel = blockIdx.y;
    const int row0 = blockIdx.x * 64;
    const float* __restrict__ rout = rout_all + (size_t)rel * NODES;
    const float* __restrict__ W = W_all + (size_t)rel * DIN * ODIM;
    ushort_t* __restrict__ mout = m_all + (size_t)rel * NODES * ODIM;

    // stage A tile [64][128] bf16
    for (int idx = tid * 8; idx < 64 * DIN; idx += 2048) {
        const int rr = idx >> 7;
        const int kk = idx & 127;
        const int row = row0 + rr;
        uint4 p = make_uint4(0u, 0u, 0u, 0u);
        if (row < NODES) p = *(const uint4*)(A + (size_t)row * DIN + kk);
        *(uint4*)(Al + rr * PAD + kk) = p;
    }
    // stage W transposed as bf16: Wt[c][k]
    for (int idx = tid; idx < ODIM * (DIN / 8); idx += 256) {
        const int c = idx % ODIM;       // coalesced on c
        const int kh = idx / ODIM;
        unsigned pk[4];
#pragma unroll
        for (int j = 0; j < 4; j++) {
            const float lo = W[(size_t)(kh * 8 + 2 * j) * ODIM + c];
            const float hi = W[(size_t)(kh * 8 + 2 * j + 1) * ODIM + c];
            pk[j] = f2bf1(lo) | (f2bf1(hi) << 16);
        }
        *(uint4*)(Wt + c * PAD + kh * 8) = *(const uint4*)pk;
    }
    __syncthreads();

    const int l = tid & 63;
    const int wv = tid >> 6;
    const int lr = l & 15;   // A row-in-tile / B col / D col
    const int lg = l >> 4;   // k-group
    f32x4 acc[NT];
#pragma unroll
    for (int j = 0; j < NT; j++) acc[j] = (f32x4){0.f, 0.f, 0.f, 0.f};

    const ushort_t* ap = Al + (wv * 16 + lr) * PAD + lg * 8;
    const ushort_t* bp = Wt + lr * PAD + lg * 8;
#pragma unroll
    for (int ks = 0; ks < DIN; ks += 32) {
        const bf16x8 af = *(const bf16x8*)(ap + ks);
#pragma unroll
        for (int j = 0; j < NT; j++) {
            const bf16x8 bfr = *(const bf16x8*)(bp + (size_t)j * 16 * PAD + ks);
            acc[j] = __builtin_amdgcn_mfma_f32_16x16x32_bf16(af, bfr, acc[j], 0, 0, 0);
        }
    }

    // D: col = l&15, row = 4*(l>>4) + reg  (m89-verified)
    const int orow0 = row0 + wv * 16 + lg * 4;
#pragma unroll
    for (int r = 0; r < 4; r++) {
        const int row = orow0 + r;
        if (row < NODES) {
            const float sc = rout[row];
#pragma unroll
            for (int j = 0; j < NT; j++)
                mout[(size_t)row * ODIM + j * 16 + lr] =
                    (ushort_t)f2bf1(acc[j][r] * sc);
        }
    }
}

// ---------------------------------------------------------------------------
// combined pull-agg over all relations + fused bias/relu epilogue.
template <int ODIM, bool L1>
__global__ __launch_bounds__(256) void agg_kernel(
    const ushort_t* __restrict__ m, const int* __restrict__ rowptr,
    const int* __restrict__ csr, const float* __restrict__ rin,
    const float* __restrict__ bias, float* __restrict__ outf,
    ushort_t* __restrict__ outh) {
    constexpr int NPB = 256 / ODIM;
    const int v = blockIdx.x * NPB + threadIdx.x / ODIM;
    const int col = threadIdx.x & (ODIM - 1);
    const int b = rowptr[v], e = rowptr[v + 1];
    const float s0 = rin[v], s1 = rin[NODES + v], s2 = rin[2 * NODES + v];
    float sum = 0.f;
    int i = b;
    for (; i + 3 < e; i += 4) {
        const int p0 = csr[i], p1 = csr[i + 1], p2 = csr[i + 2], p3 = csr[i + 3];
        const float f0 = bf2f(m[(size_t)p0 * ODIM + col]);
        const float f1 = bf2f(m[(size_t)p1 * ODIM + col]);
        const float f2 = bf2f(m[(size_t)p2 * ODIM + col]);
        const float f3 = bf2f(m[(size_t)p3 * ODIM + col]);
        const float c0 = p0 < NODES ? s0 : (p0 < 2 * NODES ? s1 : s2);
        const float c1 = p1 < NODES ? s0 : (p1 < 2 * NODES ? s1 : s2);
        const float c2 = p2 < NODES ? s0 : (p2 < 2 * NODES ? s1 : s2);
        const float c3 = p3 < NODES ? s0 : (p3 < 2 * NODES ? s1 : s2);
        sum += f0 * c0; sum += f1 * c1; sum += f2 * c2; sum += f3 * c3;
    }
    for (; i < e; i++) {
        const int p = csr[i];
        const float sc = p < NODES ? s0 : (p < 2 * NODES ? s1 : s2);
        sum += bf2f(m[(size_t)p * ODIM + col]) * sc;
    }
    const float bsum = bias[col] + bias[ODIM + col] + bias[2 * ODIM + col];
    if (L1) {
        outh[(size_t)v * ODIM + col] = (ushort_t)f2bf1(fmaxf(sum + bsum, 0.f));
    } else {
        outf[(size_t)v * ODIM + col] = sum + bsum;
    }
}

// ---------------------------------------------------------------------------
extern "C" void kernel_launch(void* const* d_in, const int* in_sizes, int n_in,
                              void* d_out, int out_size, void* d_ws, size_t ws_size,
                              hipStream_t stream) {
    const float* x  = (const float*)d_in[0];
    const int* edges = (const int*)d_in[1];
    const float* W1 = (const float*)d_in[2];
    const float* b1 = (const float*)d_in[3];
    const float* W2 = (const float*)d_in[4];
    const float* b2 = (const float*)d_in[5];
    float* out = (float*)d_out;

    char* ws = (char*)d_ws;
    size_t off = 0;
    auto alloc = [&](size_t bytes) {
        void* p = ws + off;
        off = (off + bytes + 255) & ~(size_t)255;
        return p;
    };
    float*    rout   = (float*)alloc(((size_t)NREL * NODES + NBUCK) * 4);
    unsigned* btot   = (unsigned*)rout + (size_t)NREL * NODES;
    float*    rin    = (float*)alloc((size_t)NREL * NODES * 4);
    int*      bbase  = (int*)alloc((size_t)(NBUCK + 1) * 4);
    int*      bcur   = (int*)alloc((size_t)NBUCK * 4);
    int*      rowptr = (int*)alloc((size_t)(NODES + 1) * 4);
    int*      csr    = (int*)alloc((size_t)NREL * NEDGE * 4);             // 19.2 MB
    ushort_t* m_all  = (ushort_t*)alloc((size_t)NREL * NODES * DHID * 2); // 76.8 MB
    ushort_t* h      = (ushort_t*)alloc((size_t)NODES * DHID * 2);        // 25.6 MB
    unsigned* inter  = (unsigned*)m_all;  // overlay: dead before first gemm write
    ushort_t* xb     = h;                 // overlay: dead before L1 agg writes h

    // --- CSR build (shared by both layers) ---
    hipMemsetAsync(rout, 0, ((size_t)NREL * NODES + NBUCK) * 4, stream);
    count_kernel<<<dim3(NBLK, NREL), 256, 0, stream>>>(edges, (unsigned*)rout, btot);
    bscan_kernel<<<1, 1024, 0, stream>>>(btot, bbase, bcur);
    rsq_kernel<<<(NREL * NODES + 255) / 256, 256, 0, stream>>>(rout);
    partition_kernel<<<dim3(NBLK, NREL), 256, 0, stream>>>(edges, bcur, inter);
    build_kernel<<<NBUCK, 256, 0, stream>>>(inter, bbase, csr, rowptr, rin);

    // --- x -> bf16 once (overlaid on h) ---
    tobf_kernel<<<NODES * DIN / 2048, 256, 0, stream>>>(x, xb);

    // --- layer 1: fused 3-relation MFMA GEMM + combined agg (bias+relu fused)
    mfma_gemm<DHID><<<dim3((NODES + 63) / 64, NREL), 256, 0, stream>>>(
        xb, rout, W1, m_all);
    agg_kernel<DHID, true><<<NODES / 2, 256, 0, stream>>>(
        m_all, rowptr, csr, rin, b1, nullptr, h);

    // --- layer 2 ---
    mfma_gemm<DOUT><<<dim3((NODES + 63) / 64, NREL), 256, 0, stream>>>(
        h, rout, W2, m_all);
    agg_kernel<DOUT, false><<<NODES / 4, 256, 0, stream>>>(
        m_all, rowptr, csr, rin, b2, out, nullptr);
}

// Round 6
// 674.349 us; speedup vs baseline: 4.0408x; 1.2167x over previous
//
#include <hip/hip_runtime.h>

#define NODES 100000
#define NEDGE 1600000
#define NREL  3
#define DIN   128
#define DHID  128
#define DOUT  64

#define NBUCK 782      // ceil(NODES/128), bucket = 128 dst nodes
#define CHUNK 24576    // edges per block in count/partition
#define NBLK  66       // ceil(NEDGE/CHUNK)
#define SEGCAP 8192    // per-bucket edge cap (mean 6144 -> +26 sigma)

typedef unsigned short ushort_t;
typedef __attribute__((ext_vector_type(8))) short bf16x8;
typedef __attribute__((ext_vector_type(4))) float f32x4;

__device__ __forceinline__ unsigned f2bf1(float f) {
    unsigned u = __float_as_uint(f);
    return (u + 0x7fffu + ((u >> 16) & 1u)) >> 16;   // RTNE f32->bf16
}
__device__ __forceinline__ float bf2f(ushort_t h) {
    return __uint_as_float((unsigned)h << 16);
}

// ---------------------------------------------------------------------------
// out-degree atomics (src side) + dst-bucket histogram via LDS
__global__ __launch_bounds__(256) void count_kernel(
    const int* __restrict__ edges, unsigned* __restrict__ degOut,
    unsigned* __restrict__ bucketTotal) {
    __shared__ unsigned hist[NBUCK];
    const int r = blockIdx.y;
    const int e0 = blockIdx.x * CHUNK;
    const int e1 = min(e0 + CHUNK, NEDGE);
    const int* __restrict__ src = edges + (size_t)r * 2 * NEDGE;
    const int* __restrict__ dst = src + NEDGE;
    for (int i = threadIdx.x; i < NBUCK; i += 256) hist[i] = 0;
    __syncthreads();
    for (int e = e0 + threadIdx.x; e < e1; e += 256) {
        atomicAdd(&degOut[r * NODES + src[e]], 1u);
        atomicAdd(&hist[dst[e] >> 7], 1u);
    }
    __syncthreads();
    for (int i = threadIdx.x; i < NBUCK; i += 256) {
        const unsigned c = hist[i];
        if (c) atomicAdd(&bucketTotal[i], c);
    }
}

// scan 782 bucket totals -> bucketBase[783]; init blockCursor
__global__ __launch_bounds__(1024) void bscan_kernel(
    const unsigned* __restrict__ bucketTotal, int* __restrict__ bucketBase,
    int* __restrict__ blockCursor) {
    __shared__ int wsum[16];
    const int tid = threadIdx.x, lane = tid & 63, wid = tid >> 6;
    const int v = (tid < NBUCK) ? (int)bucketTotal[tid] : 0;
    int incl = v;
    for (int off = 1; off < 64; off <<= 1) {
        const int t = __shfl_up(incl, off, 64);
        if (lane >= off) incl += t;
    }
    if (lane == 63) wsum[wid] = incl;
    __syncthreads();
    if (tid == 0) {
        int a = 0;
        for (int w = 0; w < 16; w++) { const int t = wsum[w]; wsum[w] = a; a += t; }
    }
    __syncthreads();
    const int excl = wsum[wid] + incl - v;
    if (tid <= NBUCK) bucketBase[tid] = excl;
    if (tid < NBUCK) blockCursor[tid] = excl;
}

// in-place uint out-degree -> float rsqrt(max(deg,1)), 3 planes
__global__ void rsq_kernel(float* __restrict__ buf) {
    const int i = blockIdx.x * blockDim.x + threadIdx.x;
    if (i < NREL * NODES) {
        const unsigned d = ((const unsigned*)buf)[i];
        buf[i] = rsqrtf((float)(d ? d : 1u));
    }
}

// bucket-partition edges: block reserves per-bucket runs, writes packed u32
__global__ __launch_bounds__(256) void partition_kernel(
    const int* __restrict__ edges, int* __restrict__ blockCursor,
    unsigned* __restrict__ inter) {
    __shared__ unsigned hist[NBUCK];
    __shared__ unsigned resv[NBUCK];
    const int r = blockIdx.y;
    const int e0 = blockIdx.x * CHUNK;
    const int e1 = min(e0 + CHUNK, NEDGE);
    const int* __restrict__ src = edges + (size_t)r * 2 * NEDGE;
    const int* __restrict__ dst = src + NEDGE;
    for (int i = threadIdx.x; i < NBUCK; i += 256) hist[i] = 0;
    __syncthreads();
    for (int e = e0 + threadIdx.x; e < e1; e += 256)
        atomicAdd(&hist[dst[e] >> 7], 1u);
    __syncthreads();
    for (int i = threadIdx.x; i < NBUCK; i += 256) {
        const unsigned c = hist[i];
        resv[i] = c ? (unsigned)atomicAdd(&blockCursor[i], (int)c) : 0u;
        hist[i] = 0;   // becomes rank cursor
    }
    __syncthreads();
    for (int e = e0 + threadIdx.x; e < e1; e += 256) {
        const int d = dst[e];
        const int b = d >> 7;
        const unsigned rank = atomicAdd(&hist[b], 1u);
        inter[resv[b] + rank] =
            ((unsigned)(d & 127) << 19) | (unsigned)(r * NODES + src[e]);
    }
}

// per-bucket CSR build in LDS; entries grouped by relation within each node;
// csr stores plain src id; rel counts packed into rel01; rin written here
__global__ __launch_bounds__(256) void build_kernel(
    const unsigned* __restrict__ inter, const int* __restrict__ bucketBase,
    int* __restrict__ csr, int* __restrict__ rowptr, unsigned* __restrict__ rel01,
    float* __restrict__ rin) {
    __shared__ int degR[NREL][128];
    __shared__ int rp[129];
    __shared__ int cur3[NREL][128];
    __shared__ int csr_lds[SEGCAP];
    const int b = blockIdx.x;
    const int tid = threadIdx.x;
    const int n0 = b << 7;
    const int nn = min(128, NODES - n0);
    const int s0 = bucketBase[b], s1 = bucketBase[b + 1];
    for (int i = tid; i < NREL * 128; i += 256) ((int*)degR)[i] = 0;
    __syncthreads();
    for (int s = s0 + tid; s < s1; s += 256) {
        const unsigned w = inter[s];
        const int dl = w >> 19;
        const int p = (int)(w & 0x7FFFFu);
        const int rel = p < NODES ? 0 : (p < 2 * NODES ? 1 : 2);
        atomicAdd(&degR[rel][dl], 1);
    }
    __syncthreads();
    if (tid == 0) {
        int a = 0;
        for (int i = 0; i < 128; i++) {
            rp[i] = a;
            a += degR[0][i] + degR[1][i] + degR[2][i];
        }
        rp[128] = a;
    }
    __syncthreads();
    if (tid < 128) {
        const int c0 = rp[tid];
        cur3[0][tid] = c0;
        cur3[1][tid] = c0 + degR[0][tid];
        cur3[2][tid] = c0 + degR[0][tid] + degR[1][tid];
    }
    if (tid < nn) {
        const int node = n0 + tid;
        rowptr[node] = s0 + rp[tid];
        rel01[node] = (unsigned)degR[0][tid] | ((unsigned)degR[1][tid] << 16);
#pragma unroll
        for (int r = 0; r < NREL; r++) {
            const int d = degR[r][tid];
            rin[r * NODES + node] = rsqrtf((float)(d ? d : 1));
        }
    }
    if (b == NBUCK - 1 && tid == 0) rowptr[NODES] = s1;
    __syncthreads();
    for (int s = s0 + tid; s < s1; s += 256) {
        const unsigned w = inter[s];
        const int dl = w >> 19;
        const int p = (int)(w & 0x7FFFFu);
        const int rel = p < NODES ? 0 : (p < 2 * NODES ? 1 : 2);
        const int srcn = p - rel * NODES;
        const int slot = atomicAdd(&cur3[rel][dl], 1);
        csr_lds[slot] = srcn;
    }
    __syncthreads();
    const int len = s1 - s0;
    for (int i = tid; i < len; i += 256) csr[s0 + i] = csr_lds[i];
}

// ---------------------------------------------------------------------------
// f32 -> bf16 pre-pass (8 elems/thread)
__global__ __launch_bounds__(256) void tobf_kernel(const float* __restrict__ x,
                                                   ushort_t* __restrict__ xb) {
    const size_t i = ((size_t)blockIdx.x * 256 + threadIdx.x) * 8;
    const float4 a = *(const float4*)(x + i);
    const float4 b = *(const float4*)(x + i + 4);
    uint4 p;
    p.x = f2bf1(a.x) | (f2bf1(a.y) << 16);
    p.y = f2bf1(a.z) | (f2bf1(a.w) << 16);
    p.z = f2bf1(b.x) | (f2bf1(b.y) << 16);
    p.w = f2bf1(b.z) | (f2bf1(b.w) << 16);
    *(uint4*)(xb + i) = p;
}

// ---------------------------------------------------------------------------
// MFMA GEMM: m_all[rel][row][c] = rout[rel][row] * sum_k A[row][k] * W[rel][k][c]
template <int ODIM>
__global__ __launch_bounds__(256) void mfma_gemm(
    const ushort_t* __restrict__ A, const float* __restrict__ rout_all,
    const float* __restrict__ W_all, ushort_t* __restrict__ m_all) {
    constexpr int PAD = DIN + 8;
    constexpr int NT = ODIM / 16;
    __shared__ ushort_t Al[64 * PAD];
    __shared__ ushort_t Wt[ODIM * PAD];
    const int tid = threadIdx.x;
    const int rel = blockIdx.y;
    const int row0 = blockIdx.x * 64;
    const float* __restrict__ rout = rout_all + (size_t)rel * NODES;
    const float* __restrict__ W = W_all + (size_t)rel * DIN * ODIM;
    ushort_t* __restrict__ mout = m_all + (size_t)rel * NODES * ODIM;

    for (int idx = tid * 8; idx < 64 * DIN; idx += 2048) {
        const int rr = idx >> 7;
        const int kk = idx & 127;
        const int row = row0 + rr;
        uint4 p = make_uint4(0u, 0u, 0u, 0u);
        if (row < NODES) p = *(const uint4*)(A + (size_t)row * DIN + kk);
        *(uint4*)(Al + rr * PAD + kk) = p;
    }
    for (int idx = tid; idx < ODIM * (DIN / 8); idx += 256) {
        const int c = idx % ODIM;
        const int kh = idx / ODIM;
        unsigned pk[4];
#pragma unroll
        for (int j = 0; j < 4; j++) {
            const float lo = W[(size_t)(kh * 8 + 2 * j) * ODIM + c];
            const float hi = W[(size_t)(kh * 8 + 2 * j + 1) * ODIM + c];
            pk[j] = f2bf1(lo) | (f2bf1(hi) << 16);
        }
        *(uint4*)(Wt + c * PAD + kh * 8) = *(const uint4*)pk;
    }
    __syncthreads();

    const int l = tid & 63;
    const int wv = tid >> 6;
    const int lr = l & 15;
    const int lg = l >> 4;
    f32x4 acc[NT];
#pragma unroll
    for (int j = 0; j < NT; j++) acc[j] = (f32x4){0.f, 0.f, 0.f, 0.f};

    const ushort_t* ap = Al + (wv * 16 + lr) * PAD + lg * 8;
    const ushort_t* bp = Wt + lr * PAD + lg * 8;
#pragma unroll
    for (int ks = 0; ks < DIN; ks += 32) {
        const bf16x8 af = *(const bf16x8*)(ap + ks);
#pragma unroll
        for (int j = 0; j < NT; j++) {
            const bf16x8 bfr = *(const bf16x8*)(bp + (size_t)j * 16 * PAD + ks);
            acc[j] = __builtin_amdgcn_mfma_f32_16x16x32_bf16(af, bfr, acc[j], 0, 0, 0);
        }
    }

    const int orow0 = row0 + wv * 16 + lg * 4;
#pragma unroll
    for (int r = 0; r < 4; r++) {
        const int row = orow0 + r;
        if (row < NODES) {
            const float sc = rout[row];
#pragma unroll
            for (int j = 0; j < NT; j++)
                mout[(size_t)row * ODIM + j * 16 + lr] =
                    (ushort_t)f2bf1(acc[j][r] * sc);
        }
    }
}

// ---------------------------------------------------------------------------
// pull-agg, rel-grouped CSR: 16 threads/node, 8 (or 4) cols each, uint4 gathers.
template <int ODIM, bool L1>
__global__ __launch_bounds__(256) void agg_kernel(
    const ushort_t* __restrict__ m_all, const int* __restrict__ rowptr,
    const unsigned* __restrict__ rel01, const int* __restrict__ csr,
    const float* __restrict__ rin, const float* __restrict__ bias,
    float* __restrict__ outf, ushort_t* __restrict__ outh) {
    constexpr int CPT = ODIM / 16;   // 8 (128) or 4 (64) cols per thread
    const int v = blockIdx.x * 16 + (threadIdx.x >> 4);
    const int colbase = (threadIdx.x & 15) * CPT;
    const int b = rowptr[v];
    const int e2 = rowptr[v + 1];
    const unsigned c01 = rel01[v];
    const int cnt0 = (int)(c01 & 0xffffu);
    const int cnt1 = (int)(c01 >> 16);

    float acc[CPT];
#pragma unroll
    for (int j = 0; j < CPT; j++) acc[j] = 0.f;

    const ushort_t* mr = m_all + colbase;
    int beg = b;
#pragma unroll
    for (int r = 0; r < NREL; r++) {
        const int end = (r == 0) ? b + cnt0 : (r == 1) ? b + cnt0 + cnt1 : e2;
        float s[CPT];
#pragma unroll
        for (int j = 0; j < CPT; j++) s[j] = 0.f;
#pragma unroll 2
        for (int i = beg; i < end; i++) {
            const unsigned off = (unsigned)csr[i] * ODIM;
            if constexpr (CPT == 8) {
                const uint4 p = *(const uint4*)(mr + off);
                s[0] += __uint_as_float(p.x << 16);
                s[1] += __uint_as_float(p.x & 0xffff0000u);
                s[2] += __uint_as_float(p.y << 16);
                s[3] += __uint_as_float(p.y & 0xffff0000u);
                s[4] += __uint_as_float(p.z << 16);
                s[5] += __uint_as_float(p.z & 0xffff0000u);
                s[6] += __uint_as_float(p.w << 16);
                s[7] += __uint_as_float(p.w & 0xffff0000u);
            } else {
                const uint2 p = *(const uint2*)(mr + off);
                s[0] += __uint_as_float(p.x << 16);
                s[1] += __uint_as_float(p.x & 0xffff0000u);
                s[2] += __uint_as_float(p.y << 16);
                s[3] += __uint_as_float(p.y & 0xffff0000u);
            }
        }
        const float sc = rin[r * NODES + v];
#pragma unroll
        for (int j = 0; j < CPT; j++) acc[j] = fmaf(s[j], sc, acc[j]);
        beg = end;
        mr += (size_t)NODES * ODIM;
    }

    if (L1) {
        unsigned pk[CPT / 2];
#pragma unroll
        for (int j = 0; j < CPT; j += 2) {
            const int c0 = colbase + j, c1 = colbase + j + 1;
            const float v0 = fmaxf(acc[j] + bias[c0] + bias[ODIM + c0] + bias[2 * ODIM + c0], 0.f);
            const float v1 = fmaxf(acc[j + 1] + bias[c1] + bias[ODIM + c1] + bias[2 * ODIM + c1], 0.f);
            pk[j / 2] = f2bf1(v0) | (f2bf1(v1) << 16);
        }
        *(uint4*)(outh + (size_t)v * ODIM + colbase) = *(const uint4*)pk;
    } else {
        float o[CPT];
#pragma unroll
        for (int j = 0; j < CPT; j++) {
            const int c = colbase + j;
            o[j] = acc[j] + bias[c] + bias[ODIM + c] + bias[2 * ODIM + c];
        }
        *(float4*)(outf + (size_t)v * ODIM + colbase) = *(const float4*)o;
    }
}

// ---------------------------------------------------------------------------
extern "C" void kernel_launch(void* const* d_in, const int* in_sizes, int n_in,
                              void* d_out, int out_size, void* d_ws, size_t ws_size,
                              hipStream_t stream) {
    const float* x  = (const float*)d_in[0];
    const int* edges = (const int*)d_in[1];
    const float* W1 = (const float*)d_in[2];
    const float* b1 = (const float*)d_in[3];
    const float* W2 = (const float*)d_in[4];
    const float* b2 = (const float*)d_in[5];
    float* out = (float*)d_out;

    char* ws = (char*)d_ws;
    size_t off = 0;
    auto alloc = [&](size_t bytes) {
        void* p = ws + off;
        off = (off + bytes + 255) & ~(size_t)255;
        return p;
    };
    float*    rout   = (float*)alloc(((size_t)NREL * NODES + NBUCK) * 4);
    unsigned* btot   = (unsigned*)rout + (size_t)NREL * NODES;
    float*    rin    = (float*)alloc((size_t)NREL * NODES * 4);
    int*      bbase  = (int*)alloc((size_t)(NBUCK + 1) * 4);
    int*      bcur   = (int*)alloc((size_t)NBUCK * 4);
    int*      rowptr = (int*)alloc((size_t)(NODES + 1) * 4);
    unsigned* rel01  = (unsigned*)alloc((size_t)NODES * 4);
    int*      csr    = (int*)alloc((size_t)NREL * NEDGE * 4);             // 19.2 MB
    ushort_t* m_all  = (ushort_t*)alloc((size_t)NREL * NODES * DHID * 2); // 76.8 MB
    ushort_t* h      = (ushort_t*)alloc((size_t)NODES * DHID * 2);        // 25.6 MB
    unsigned* inter  = (unsigned*)m_all;  // overlay: dead before first gemm write
    ushort_t* xb     = h;                 // overlay: dead before L1 agg writes h

    // --- CSR build (shared by both layers) ---
    hipMemsetAsync(rout, 0, ((size_t)NREL * NODES + NBUCK) * 4, stream);
    count_kernel<<<dim3(NBLK, NREL), 256, 0, stream>>>(edges, (unsigned*)rout, btot);
    bscan_kernel<<<1, 1024, 0, stream>>>(btot, bbase, bcur);
    rsq_kernel<<<(NREL * NODES + 255) / 256, 256, 0, stream>>>(rout);
    partition_kernel<<<dim3(NBLK, NREL), 256, 0, stream>>>(edges, bcur, inter);
    build_kernel<<<NBUCK, 256, 0, stream>>>(inter, bbase, csr, rowptr, rel01, rin);

    // --- x -> bf16 once (overlaid on h) ---
    tobf_kernel<<<NODES * DIN / 2048, 256, 0, stream>>>(x, xb);

    // --- layer 1 ---
    mfma_gemm<DHID><<<dim3((NODES + 63) / 64, NREL), 256, 0, stream>>>(
        xb, rout, W1, m_all);
    agg_kernel<DHID, true><<<NODES / 16, 256, 0, stream>>>(
        m_all, rowptr, rel01, csr, rin, b1, nullptr, h);

    // --- layer 2 ---
    mfma_gemm<DOUT><<<dim3((NODES + 63) / 64, NREL), 256, 0, stream>>>(
        h, rout, W2, m_all);
    agg_kernel<DOUT, false><<<NODES / 16, 256, 0, stream>>>(
        m_all, rowptr, rel01, csr, rin, b2, out, nullptr);
}

// Round 7
// 626.322 us; speedup vs baseline: 4.3507x; 1.0767x over previous
//
#include <hip/hip_runtime.h>

#define NODES 100000
#define NEDGE 1600000
#define NREL  3
#define DIN   128
#define DHID  128
#define DOUT  64

#define NBUCK 782      // ceil(NODES/128), bucket = 128 dst nodes
#define CHUNK 8192     // edges per block in partition
#define NBLK  196      // ceil(NEDGE/CHUNK)
#define SEGCAP 8192    // fixed per-bucket capacity (mean 6144, sigma 78 -> +26 sigma)

typedef unsigned short ushort_t;
typedef __attribute__((ext_vector_type(8))) short bf16x8;
typedef __attribute__((ext_vector_type(4))) float f32x4;

__device__ __forceinline__ unsigned f2bf1(float f) {
    unsigned u = __float_as_uint(f);
    return (u + 0x7fffu + ((u >> 16) & 1u)) >> 16;   // RTNE f32->bf16
}

// ---------------------------------------------------------------------------
// single edge scan: degOut atomics + bucket-partition with block-level
// run reservation into fixed-capacity buckets (no count pre-pass needed)
__global__ __launch_bounds__(256) void partition_kernel(
    const int* __restrict__ edges, unsigned* __restrict__ degOut,
    int* __restrict__ bcur, unsigned* __restrict__ inter) {
    __shared__ unsigned hist[NBUCK];
    __shared__ unsigned resv[NBUCK];
    const int r = blockIdx.y;
    const int e0 = blockIdx.x * CHUNK;
    const int e1 = min(e0 + CHUNK, NEDGE);
    const int* __restrict__ src = edges + (size_t)r * 2 * NEDGE;
    const int* __restrict__ dst = src + NEDGE;
    for (int i = threadIdx.x; i < NBUCK; i += 256) hist[i] = 0;
    __syncthreads();
    for (int e = e0 + threadIdx.x; e < e1; e += 256) {
        atomicAdd(&degOut[r * NODES + src[e]], 1u);
        atomicAdd(&hist[dst[e] >> 7], 1u);
    }
    __syncthreads();
    for (int i = threadIdx.x; i < NBUCK; i += 256) {
        const unsigned c = hist[i];
        resv[i] = c ? (unsigned)atomicAdd(&bcur[i], (int)c) : 0u;
        hist[i] = 0;   // becomes rank cursor
    }
    __syncthreads();
    for (int e = e0 + threadIdx.x; e < e1; e += 256) {
        const int d = dst[e];
        const int b = d >> 7;
        const unsigned rank = atomicAdd(&hist[b], 1u);
        inter[(size_t)b * SEGCAP + resv[b] + rank] =
            ((unsigned)(d & 127) << 19) | (unsigned)(r * NODES + src[e]);
    }
}

// scan 782 actual bucket counts -> bucketBase[783]
__global__ __launch_bounds__(1024) void bscan_kernel(
    const int* __restrict__ bcur, int* __restrict__ bucketBase) {
    __shared__ int wsum[16];
    const int tid = threadIdx.x, lane = tid & 63, wid = tid >> 6;
    const int v = (tid < NBUCK) ? bcur[tid] : 0;
    int incl = v;
    for (int off = 1; off < 64; off <<= 1) {
        const int t = __shfl_up(incl, off, 64);
        if (lane >= off) incl += t;
    }
    if (lane == 63) wsum[wid] = incl;
    __syncthreads();
    if (tid == 0) {
        int a = 0;
        for (int w = 0; w < 16; w++) { const int t = wsum[w]; wsum[w] = a; a += t; }
    }
    __syncthreads();
    const int excl = wsum[wid] + incl - v;
    if (tid <= NBUCK) bucketBase[tid] = excl;
}

// in-place uint out-degree -> float rsqrt(max(deg,1)), 3 planes
__global__ void rsq_kernel(float* __restrict__ buf) {
    const int i = blockIdx.x * blockDim.x + threadIdx.x;
    if (i < NREL * NODES) {
        const unsigned d = ((const unsigned*)buf)[i];
        buf[i] = rsqrtf((float)(d ? d : 1u));
    }
}

// per-bucket CSR build in LDS; entries grouped by relation within each node;
// csr stores plain src id; rel counts packed into rel01; rin written here
__global__ __launch_bounds__(256) void build_kernel(
    const unsigned* __restrict__ inter, const int* __restrict__ bucketBase,
    int* __restrict__ csr, int* __restrict__ rowptr, unsigned* __restrict__ rel01,
    float* __restrict__ rin) {
    __shared__ int degR[NREL][128];
    __shared__ int rp[129];
    __shared__ int cur3[NREL][128];
    __shared__ int csr_lds[SEGCAP];
    const int b = blockIdx.x;
    const int tid = threadIdx.x;
    const int n0 = b << 7;
    const int nn = min(128, NODES - n0);
    const int s0 = bucketBase[b], s1 = bucketBase[b + 1];
    const int len = s1 - s0;
    const unsigned* __restrict__ seg = inter + (size_t)b * SEGCAP;
    for (int i = tid; i < NREL * 128; i += 256) ((int*)degR)[i] = 0;
    __syncthreads();
    for (int s = tid; s < len; s += 256) {
        const unsigned w = seg[s];
        const int dl = w >> 19;
        const int p = (int)(w & 0x7FFFFu);
        const int rel = p < NODES ? 0 : (p < 2 * NODES ? 1 : 2);
        atomicAdd(&degR[rel][dl], 1);
    }
    __syncthreads();
    if (tid == 0) {
        int a = 0;
        for (int i = 0; i < 128; i++) {
            rp[i] = a;
            a += degR[0][i] + degR[1][i] + degR[2][i];
        }
        rp[128] = a;
    }
    __syncthreads();
    if (tid < 128) {
        const int c0 = rp[tid];
        cur3[0][tid] = c0;
        cur3[1][tid] = c0 + degR[0][tid];
        cur3[2][tid] = c0 + degR[0][tid] + degR[1][tid];
    }
    if (tid < nn) {
        const int node = n0 + tid;
        rowptr[node] = s0 + rp[tid];
        rel01[node] = (unsigned)degR[0][tid] | ((unsigned)degR[1][tid] << 16);
#pragma unroll
        for (int r = 0; r < NREL; r++) {
            const int d = degR[r][tid];
            rin[r * NODES + node] = rsqrtf((float)(d ? d : 1));
        }
    }
    if (b == NBUCK - 1 && tid == 0) rowptr[NODES] = s1;
    __syncthreads();
    for (int s = tid; s < len; s += 256) {
        const unsigned w = seg[s];
        const int dl = w >> 19;
        const int p = (int)(w & 0x7FFFFu);
        const int rel = p < NODES ? 0 : (p < 2 * NODES ? 1 : 2);
        const int srcn = p - rel * NODES;
        const int slot = atomicAdd(&cur3[rel][dl], 1);
        csr_lds[slot] = srcn;
    }
    __syncthreads();
    for (int i = tid; i < len; i += 256) csr[s0 + i] = csr_lds[i];
}

// ---------------------------------------------------------------------------
// f32 -> bf16 pre-pass (8 elems/thread)
__global__ __launch_bounds__(256) void tobf_kernel(const float* __restrict__ x,
                                                   ushort_t* __restrict__ xb) {
    const size_t i = ((size_t)blockIdx.x * 256 + threadIdx.x) * 8;
    const float4 a = *(const float4*)(x + i);
    const float4 b = *(const float4*)(x + i + 4);
    uint4 p;
    p.x = f2bf1(a.x) | (f2bf1(a.y) << 16);
    p.y = f2bf1(a.z) | (f2bf1(a.w) << 16);
    p.z = f2bf1(b.x) | (f2bf1(b.y) << 16);
    p.w = f2bf1(b.z) | (f2bf1(b.w) << 16);
    *(uint4*)(xb + i) = p;
}

// ---------------------------------------------------------------------------
// MFMA GEMM: m_all[rel][row][c] = rout[rel][row] * sum_k A[row][k] * W[rel][k][c]
template <int ODIM>
__global__ __launch_bounds__(256) void mfma_gemm(
    const ushort_t* __restrict__ A, const float* __restrict__ rout_all,
    const float* __restrict__ W_all, ushort_t* __restrict__ m_all) {
    constexpr int PAD = DIN + 8;
    constexpr int NT = ODIM / 16;
    __shared__ ushort_t Al[64 * PAD];
    __shared__ ushort_t Wt[ODIM * PAD];
    const int tid = threadIdx.x;
    const int rel = blockIdx.y;
    const int row0 = blockIdx.x * 64;
    const float* __restrict__ rout = rout_all + (size_t)rel * NODES;
    const float* __restrict__ W = W_all + (size_t)rel * DIN * ODIM;
    ushort_t* __restrict__ mout = m_all + (size_t)rel * NODES * ODIM;

    for (int idx = tid * 8; idx < 64 * DIN; idx += 2048) {
        const int rr = idx >> 7;
        const int kk = idx & 127;
        const int row = row0 + rr;
        uint4 p = make_uint4(0u, 0u, 0u, 0u);
        if (row < NODES) p = *(const uint4*)(A + (size_t)row * DIN + kk);
        *(uint4*)(Al + rr * PAD + kk) = p;
    }
    for (int idx = tid; idx < ODIM * (DIN / 8); idx += 256) {
        const int c = idx % ODIM;
        const int kh = idx / ODIM;
        unsigned pk[4];
#pragma unroll
        for (int j = 0; j < 4; j++) {
            const float lo = W[(size_t)(kh * 8 + 2 * j) * ODIM + c];
            const float hi = W[(size_t)(kh * 8 + 2 * j + 1) * ODIM + c];
            pk[j] = f2bf1(lo) | (f2bf1(hi) << 16);
        }
        *(uint4*)(Wt + c * PAD + kh * 8) = *(const uint4*)pk;
    }
    __syncthreads();

    const int l = tid & 63;
    const int wv = tid >> 6;
    const int lr = l & 15;
    const int lg = l >> 4;
    f32x4 acc[NT];
#pragma unroll
    for (int j = 0; j < NT; j++) acc[j] = (f32x4){0.f, 0.f, 0.f, 0.f};

    const ushort_t* ap = Al + (wv * 16 + lr) * PAD + lg * 8;
    const ushort_t* bp = Wt + lr * PAD + lg * 8;
#pragma unroll
    for (int ks = 0; ks < DIN; ks += 32) {
        const bf16x8 af = *(const bf16x8*)(ap + ks);
#pragma unroll
        for (int j = 0; j < NT; j++) {
            const bf16x8 bfr = *(const bf16x8*)(bp + (size_t)j * 16 * PAD + ks);
            acc[j] = __builtin_amdgcn_mfma_f32_16x16x32_bf16(af, bfr, acc[j], 0, 0, 0);
        }
    }

    const int orow0 = row0 + wv * 16 + lg * 4;
#pragma unroll
    for (int r = 0; r < 4; r++) {
        const int row = orow0 + r;
        if (row < NODES) {
            const float sc = rout[row];
#pragma unroll
            for (int j = 0; j < NT; j++)
                mout[(size_t)row * ODIM + j * 16 + lr] =
                    (ushort_t)f2bf1(acc[j][r] * sc);
        }
    }
}

// ---------------------------------------------------------------------------
// pull-agg, rel-grouped CSR: 16 threads/node, 8 (or 4) cols each, uint4 gathers.
template <int ODIM, bool L1>
__global__ __launch_bounds__(256) void agg_kernel(
    const ushort_t* __restrict__ m_all, const int* __restrict__ rowptr,
    const unsigned* __restrict__ rel01, const int* __restrict__ csr,
    const float* __restrict__ rin, const float* __restrict__ bias,
    float* __restrict__ outf, ushort_t* __restrict__ outh) {
    constexpr int CPT = ODIM / 16;   // 8 (128) or 4 (64) cols per thread
    const int v = blockIdx.x * 16 + (threadIdx.x >> 4);
    const int colbase = (threadIdx.x & 15) * CPT;
    const int b = rowptr[v];
    const int e2 = rowptr[v + 1];
    const unsigned c01 = rel01[v];
    const int cnt0 = (int)(c01 & 0xffffu);
    const int cnt1 = (int)(c01 >> 16);

    float acc[CPT];
#pragma unroll
    for (int j = 0; j < CPT; j++) acc[j] = 0.f;

    const ushort_t* mr = m_all + colbase;
    int beg = b;
#pragma unroll
    for (int r = 0; r < NREL; r++) {
        const int end = (r == 0) ? b + cnt0 : (r == 1) ? b + cnt0 + cnt1 : e2;
        float s[CPT];
#pragma unroll
        for (int j = 0; j < CPT; j++) s[j] = 0.f;
#pragma unroll 2
        for (int i = beg; i < end; i++) {
            const unsigned off = (unsigned)csr[i] * ODIM;
            if constexpr (CPT == 8) {
                const uint4 p = *(const uint4*)(mr + off);
                s[0] += __uint_as_float(p.x << 16);
                s[1] += __uint_as_float(p.x & 0xffff0000u);
                s[2] += __uint_as_float(p.y << 16);
                s[3] += __uint_as_float(p.y & 0xffff0000u);
                s[4] += __uint_as_float(p.z << 16);
                s[5] += __uint_as_float(p.z & 0xffff0000u);
                s[6] += __uint_as_float(p.w << 16);
                s[7] += __uint_as_float(p.w & 0xffff0000u);
            } else {
                const uint2 p = *(const uint2*)(mr + off);
                s[0] += __uint_as_float(p.x << 16);
                s[1] += __uint_as_float(p.x & 0xffff0000u);
                s[2] += __uint_as_float(p.y << 16);
                s[3] += __uint_as_float(p.y & 0xffff0000u);
            }
        }
        const float sc = rin[r * NODES + v];
#pragma unroll
        for (int j = 0; j < CPT; j++) acc[j] = fmaf(s[j], sc, acc[j]);
        beg = end;
        mr += (size_t)NODES * ODIM;
    }

    if (L1) {
        unsigned pk[CPT / 2];
#pragma unroll
        for (int j = 0; j < CPT; j += 2) {
            const int c0 = colbase + j, c1 = colbase + j + 1;
            const float v0 = fmaxf(acc[j] + bias[c0] + bias[ODIM + c0] + bias[2 * ODIM + c0], 0.f);
            const float v1 = fmaxf(acc[j + 1] + bias[c1] + bias[ODIM + c1] + bias[2 * ODIM + c1], 0.f);
            pk[j / 2] = f2bf1(v0) | (f2bf1(v1) << 16);
        }
        *(uint4*)(outh + (size_t)v * ODIM + colbase) = *(const uint4*)pk;
    } else {
        float o[CPT];
#pragma unroll
        for (int j = 0; j < CPT; j++) {
            const int c = colbase + j;
            o[j] = acc[j] + bias[c] + bias[ODIM + c] + bias[2 * ODIM + c];
        }
        *(float4*)(outf + (size_t)v * ODIM + colbase) = *(const float4*)o;
    }
}

// ---------------------------------------------------------------------------
extern "C" void kernel_launch(void* const* d_in, const int* in_sizes, int n_in,
                              void* d_out, int out_size, void* d_ws, size_t ws_size,
                              hipStream_t stream) {
    const float* x  = (const float*)d_in[0];
    const int* edges = (const int*)d_in[1];
    const float* W1 = (const float*)d_in[2];
    const float* b1 = (const float*)d_in[3];
    const float* W2 = (const float*)d_in[4];
    const float* b2 = (const float*)d_in[5];
    float* out = (float*)d_out;

    char* ws = (char*)d_ws;
    size_t off = 0;
    auto alloc = [&](size_t bytes) {
        void* p = ws + off;
        off = (off + bytes + 255) & ~(size_t)255;
        return p;
    };
    // rout (3N degOut/rsq planes) + bcur adjacent -> single memset
    float*    rout   = (float*)alloc(((size_t)NREL * NODES + NBUCK) * 4);
    int*      bcur   = (int*)rout + (size_t)NREL * NODES;
    float*    rin    = (float*)alloc((size_t)NREL * NODES * 4);
    int*      bbase  = (int*)alloc((size_t)(NBUCK + 1) * 4);
    int*      rowptr = (int*)alloc((size_t)(NODES + 1) * 4);
    unsigned* rel01  = (unsigned*)alloc((size_t)NODES * 4);
    int*      csr    = (int*)alloc((size_t)NREL * NEDGE * 4);             // 19.2 MB
    ushort_t* m_all  = (ushort_t*)alloc((size_t)NREL * NODES * DHID * 2); // 76.8 MB
    ushort_t* h      = (ushort_t*)alloc((size_t)NODES * DHID * 2);        // 25.6 MB
    unsigned* inter  = (unsigned*)m_all;  // 25.6 MB overlay: dead before gemm writes
    ushort_t* xb     = h;                 // overlay: dead before L1 agg writes h

    // --- CSR build: one fused edge scan + per-bucket build ---
    hipMemsetAsync(rout, 0, ((size_t)NREL * NODES + NBUCK) * 4, stream);
    partition_kernel<<<dim3(NBLK, NREL), 256, 0, stream>>>(
        edges, (unsigned*)rout, bcur, inter);
    bscan_kernel<<<1, 1024, 0, stream>>>(bcur, bbase);
    rsq_kernel<<<(NREL * NODES + 255) / 256, 256, 0, stream>>>(rout);
    build_kernel<<<NBUCK, 256, 0, stream>>>(inter, bbase, csr, rowptr, rel01, rin);

    // --- x -> bf16 once (overlaid on h) ---
    tobf_kernel<<<NODES * DIN / 2048, 256, 0, stream>>>(x, xb);

    // --- layer 1 ---
    mfma_gemm<DHID><<<dim3((NODES + 63) / 64, NREL), 256, 0, stream>>>(
        xb, rout, W1, m_all);
    agg_kernel<DHID, true><<<NODES / 16, 256, 0, stream>>>(
        m_all, rowptr, rel01, csr, rin, b1, nullptr, h);

    // --- layer 2 ---
    mfma_gemm<DOUT><<<dim3((NODES + 63) / 64, NREL), 256, 0, stream>>>(
        h, rout, W2, m_all);
    agg_kernel<DOUT, false><<<NODES / 16, 256, 0, stream>>>(
        m_all, rowptr, rel01, csr, rin, b2, out, nullptr);
}